// Round 7
// baseline (1604.796 us; speedup 1.0000x reference)
//
#include <hip/hip_runtime.h>
#include <hip/hip_bf16.h>

typedef unsigned short u16;
typedef unsigned int   u32;
typedef __attribute__((ext_vector_type(8))) short bf16x8;
typedef __attribute__((ext_vector_type(4))) float f32x4;

#define HDIM 128
#define TSTEPS 12
#define OUTD 64
#define NTMAJ 1536           /* 12*128 elems per node (node-major) */
#define NTB   3072           /* bytes per node row */

#define AS1 __attribute__((address_space(1)))
#define AS3 __attribute__((address_space(3)))

struct u32x3 { u32 x, y, z; };

__device__ __forceinline__ void glds16(const void* g, void* l) {
  __builtin_amdgcn_global_load_lds((const AS1 u32*)g, (AS3 u32*)l, 16, 0, 0);
}

__device__ __forceinline__ float bflo(u32 u) { return __uint_as_float(u << 16); }
__device__ __forceinline__ float bfhi(u32 u) { return __uint_as_float(u & 0xffff0000u); }
__device__ __forceinline__ u16 f2bf(float x) {
  union { float f; u32 u; } v; v.f = x;
  return (u16)((v.u + 0x7fffu + ((v.u >> 16) & 1u)) >> 16);
}
__device__ __forceinline__ float sigm(float x) { return 1.0f / (1.0f + __expf(-x)); }
__device__ __forceinline__ float tanh_f(float x) { return 1.0f - 2.0f / (__expf(2.0f * x) + 1.0f); }

// ---------------- setup kernels ----------------

__global__ void k_init(int* cnt, int* cursor, int N) {
  int i = blockIdx.x * 256 + threadIdx.x;
  if (i < N) { cnt[i] = 1; cursor[i] = 0; }   // cnt=1 reserves the self-loop slot
}

__global__ void k_zero(u32* p, int n) {
  int i = blockIdx.x * 256 + threadIdx.x;
  if (i < n) p[i] = 0;
}

// x (N,128,12) f32 -> xb (12,N,128) bf16 (time-major)
__global__ void k_xpose(const float* __restrict__ x, u16* __restrict__ xb, int N) {
  int i = blockIdx.x * 256 + threadIdx.x;  // (n,f)
  if (i >= N * HDIM) return;
  const float* src = x + (size_t)i * 12;
  float4 a = *(const float4*)src;
  float4 b = *(const float4*)(src + 4);
  float4 c = *(const float4*)(src + 8);
  float v[12] = { a.x,a.y,a.z,a.w,b.x,b.y,b.z,b.w,c.x,c.y,c.z,c.w };
#pragma unroll
  for (int t = 0; t < 12; ++t) xb[(size_t)t * N * HDIM + i] = f2bf(v[t]);
}

__global__ void k_cnt(const int* __restrict__ ei, int* cnt, int E) {
  int e = blockIdx.x * 256 + threadIdx.x;
  if (e >= E) return;
  atomicAdd(&cnt[ei[E + e]], 1);
}

__global__ void k_scan(const int* __restrict__ cnt, int* __restrict__ rp, int n) {
  __shared__ int sums[1024];
  int tid = threadIdx.x;
  int chunk = (n + 1023) / 1024;
  int start = tid * chunk;
  int end = start + chunk; if (end > n) end = n;
  int s = 0;
  for (int i = start; i < end; ++i) s += cnt[i];
  sums[tid] = s;
  __syncthreads();
  for (int off = 1; off < 1024; off <<= 1) {
    int v = (tid >= off) ? sums[tid - off] : 0;
    __syncthreads();
    sums[tid] += v;
    __syncthreads();
  }
  int run = (tid == 0) ? 0 : sums[tid - 1];
  for (int i = start; i < end; ++i) { rp[i] = run; run += cnt[i]; }
  if (tid == 1023) rp[n] = sums[1023];
}

// edges -> interleaved {src_node_byteoff (node-major), raw_w}; slot rp[col]+0 reserved for self
__global__ void k_scatter(const int* __restrict__ ei, const float* __restrict__ ea,
                          const int* __restrict__ rp, int* cursor, uint2* ee, int E) {
  int e = blockIdx.x * 256 + threadIdx.x;
  if (e >= E) return;
  int row = ei[e], col = ei[E + e];
  int pos = atomicAdd(&cursor[col], 1);
  int idx = rp[col] + 1 + pos;
  ee[idx] = make_uint2((u32)row * NTB, __float_as_uint(ea[e * 4 + 3]));
}

__global__ void k_degcsr(const int* __restrict__ rp, uint2* ee, float* dis, int N) {
  int j = blockIdx.x;
  int lane = threadIdx.x;  // 64
  int beg = rp[j], end = rp[j + 1];
  float s = 0.f;
  for (int i = beg + 1 + lane; i < end; i += 64) s += __uint_as_float(ee[i].y);
#pragma unroll
  for (int o = 32; o; o >>= 1) s += __shfl_down(s, o);
  if (lane == 0) {
    dis[j] = rsqrtf(1.0f + s);
    ee[beg] = make_uint2((u32)j * NTB, __float_as_uint(1.0f));  // self-loop raw w = 1
  }
}

__global__ void k_enrm(const int* __restrict__ rp, const float* __restrict__ dis,
                       uint2* ee, int N) {
  int j = blockIdx.x;
  int lane = threadIdx.x;  // 64
  int beg = rp[j], end = rp[j + 1];
  float dj = dis[j];
  for (int i = beg + lane; i < end; i += 64) {
    uint2 q = ee[i];
    ee[i].y = __float_as_uint(dis[q.x / NTB] * __uint_as_float(q.y) * dj);
  }
}

// src (K,J) f32 row-major -> dst[j*ldK + k] bf16 (transposed)
__global__ void k_wt(const float* __restrict__ src, u16* __restrict__ dst, int K, int J, int ldK) {
  int idx = blockIdx.x * 256 + threadIdx.x;
  if (idx >= K * J) return;
  int k = idx / J, j = idx % J;
  dst[j * ldK + k] = f2bf(src[idx]);
}

// fused gate weights, column-permuted: p[3:0]=hc_lo, p[5:4]=gate, p[8:6]=hc_hi
__global__ void k_wt4(const float* wf, const float* wi, const float* wo, const float* wc,
                      u16* __restrict__ dst) {
  int idx = blockIdx.x * 256 + threadIdx.x;  // 512*384
  if (idx >= 512 * 384) return;
  int p = idx / 384, k = idx % 384;
  int g = (p >> 4) & 3;
  int hc = (p & 15) | ((p >> 6) << 4);
  const float* w[4] = { wf, wi, wo, wc };
  dst[p * 384 + k] = f2bf(w[g][k * HDIM + hc]);
}

__global__ void k_bias4(const float* bf, const float* bi, const float* bo, const float* bc,
                        float* dst) {
  int p = blockIdx.x * 256 + threadIdx.x;
  if (p >= 512) return;
  int g = (p >> 4) & 3;
  int hc = (p & 15) | ((p >> 6) << 4);
  const float* b[4] = { bf, bi, bo, bc };
  dst[p] = b[g][hc];
}

// ---------------- batched GCN linear: out[node-major] = A_t @ gwT^T, grid (nb, 12) ----------------
// A_t = A + t*nh, rows stride HDIM (time-major slabs). Output node-major.
__global__ __launch_bounds__(256)
void k_gcnlin(const u16* __restrict__ A, const u16* __restrict__ wt,
              u16* __restrict__ out, int N, int nh) {
  __shared__ u16 lA[128 * 32];
  __shared__ u16 lB[128 * 32];
  const int t = blockIdx.y;
  const int tid = threadIdx.x;
  const int row0 = blockIdx.x * 128;
  const int wave = tid >> 6, lane = tid & 63;
  const int wm = (wave >> 1) * 64, wn = (wave & 1) * 64;
  const int fr = lane & 15, fk = (lane >> 4) * 8;
  const int lr = tid >> 2, lc = (tid & 3) * 8;
  u16* ldA = lA + wave * 512;
  u16* ldB = lB + wave * 512;
  const u16* ga1 = A + (size_t)t * nh + (size_t)(row0 + lr) * HDIM + lc;
  const u16* ga2 = ga1 + (size_t)64 * HDIM;
  const u16* gb1 = wt + (size_t)lr * HDIM + lc;
  const u16* gb2 = gb1 + (size_t)64 * HDIM;

  f32x4 acc[4][4] = {};
  for (int k0 = 0; k0 < 128; k0 += 32) {
    glds16(ga1 + k0, ldA);
    glds16(ga2 + k0, ldA + 2048);
    glds16(gb1 + k0, ldB);
    glds16(gb2 + k0, ldB + 2048);
    __syncthreads();
    bf16x8 af[4], bfx[4];
#pragma unroll
    for (int m = 0; m < 4; ++m) af[m]  = *(const bf16x8*)&lA[(wm + m * 16 + fr) * 32 + fk];
#pragma unroll
    for (int n = 0; n < 4; ++n) bfx[n] = *(const bf16x8*)&lB[(wn + n * 16 + fr) * 32 + fk];
#pragma unroll
    for (int m = 0; m < 4; ++m)
#pragma unroll
      for (int n = 0; n < 4; ++n)
        acc[m][n] = __builtin_amdgcn_mfma_f32_16x16x32_bf16(af[m], bfx[n], acc[m][n], 0, 0, 0);
    __syncthreads();
  }
  const int fq4 = (lane >> 4) * 4;
#pragma unroll
  for (int m = 0; m < 4; ++m)
#pragma unroll
    for (int n = 0; n < 4; ++n) {
      const int colg = wn + n * 16 + fr;
#pragma unroll
      for (int i = 0; i < 4; ++i) {
        const int rowg = row0 + wm + m * 16 + fq4 + i;
        if (rowg < N) out[(size_t)rowg * NTMAJ + t * HDIM + colg] = f2bf(acc[m][n][i]);
      }
    }
}

// ---------------- 3-segment gate GEMM (K=384) + LSTM cell epilogue, grid (nb, 4) ----------------
// Segments: (p0,st0)=x_t, (p1,st1)=g_t, (p2,st2)=h_prev; W = 512x384 col-permuted.
__global__ __launch_bounds__(256)
void k_gate3(const u16* __restrict__ p0, u32 st0,
             const u16* __restrict__ p1, u32 st1,
             const u16* __restrict__ p2, u32 st2,
             const u16* __restrict__ wt, const float* __restrict__ b4p,
             float* __restrict__ cst, u16* __restrict__ hout, int M) {
  __shared__ u16 lA[128 * 32];
  __shared__ u16 lB[128 * 32];
  const int col0 = blockIdx.y * 128;
  const int tid = threadIdx.x;
  const int row0 = blockIdx.x * 128;
  const int wave = tid >> 6, lane = tid & 63;
  const int wm = (wave >> 1) * 64, wn = (wave & 1) * 64;
  const int fr = lane & 15, fk = (lane >> 4) * 8;
  const int lr = tid >> 2, lc = (tid & 3) * 8;
  u16* ldA = lA + wave * 512;
  u16* ldB = lB + wave * 512;
  const u16* a1[3]; const u16* a2[3];
  a1[0] = p0 + (size_t)(row0 + lr) * st0 + lc;  a2[0] = a1[0] + (size_t)64 * st0;
  a1[1] = p1 + (size_t)(row0 + lr) * st1 + lc;  a2[1] = a1[1] + (size_t)64 * st1;
  a1[2] = p2 + (size_t)(row0 + lr) * st2 + lc;  a2[2] = a1[2] + (size_t)64 * st2;
  const u16* gb1 = wt + (size_t)(col0 + lr) * 384 + lc;
  const u16* gb2 = gb1 + (size_t)64 * 384;

  f32x4 acc[4][4] = {};
#pragma unroll
  for (int ks = 0; ks < 12; ++ks) {
    const int seg = ks >> 2;
    const int kk = (ks & 3) * 32;
    glds16(a1[seg] + kk, ldA);
    glds16(a2[seg] + kk, ldA + 2048);
    glds16(gb1 + ks * 32, ldB);
    glds16(gb2 + ks * 32, ldB + 2048);
    __syncthreads();
    bf16x8 af[4], bfx[4];
#pragma unroll
    for (int m = 0; m < 4; ++m) af[m]  = *(const bf16x8*)&lA[(wm + m * 16 + fr) * 32 + fk];
#pragma unroll
    for (int n = 0; n < 4; ++n) bfx[n] = *(const bf16x8*)&lB[(wn + n * 16 + fr) * 32 + fk];
#pragma unroll
    for (int m = 0; m < 4; ++m)
#pragma unroll
      for (int n = 0; n < 4; ++n)
        acc[m][n] = __builtin_amdgcn_mfma_f32_16x16x32_bf16(af[m], bfx[n], acc[m][n], 0, 0, 0);
    __syncthreads();
  }

  // epilogue: lane's 4 n-fragments are gates f,i,o,c of channel hc
  const int fq4 = (lane >> 4) * 4;
  const int hc = fr | ((blockIdx.y * 2 + (wave & 1)) << 4);
  const int colbase = col0 + wn + fr;
  const float bb0 = b4p[colbase];
  const float bb1 = b4p[colbase + 16];
  const float bb2 = b4p[colbase + 32];
  const float bb3 = b4p[colbase + 48];
#pragma unroll
  for (int m = 0; m < 4; ++m)
#pragma unroll
    for (int i = 0; i < 4; ++i) {
      const int rowg = row0 + wm + m * 16 + fq4 + i;
      if (rowg < M) {
        float f_ = sigm(acc[m][0][i] + bb0);
        float i_ = sigm(acc[m][1][i] + bb1);
        float o_ = sigm(acc[m][2][i] + bb2);
        float cd = tanh_f(acc[m][3][i] + bb3);
        size_t idx = (size_t)rowg * HDIM + hc;
        float cn = f_ * cst[idx] + i_ * cd;
        cst[idx] = cn;
        hout[idx] = f2bf(o_ * tanh_f(cn));
      }
    }
}

// ---------------- node-major batched aggregation + sigmoid (all 12 t per block) ----------------
__global__ void k_aggB(const u16* __restrict__ xw, const int* __restrict__ rp,
                       const uint2* __restrict__ ee, const float* __restrict__ gbias,
                       u16* __restrict__ g, int N) {
  __shared__ uint2 s_e[256];
  __shared__ float s_b[128];
  const int j = blockIdx.x;
  const int tid = threadIdx.x;
  if (tid < 128) s_b[tid] = gbias[tid];
  const int beg = rp[j], end = rp[j + 1];
  const char* base = (const char*)xw;
  const u32 myoff = (u32)tid * 12;
  float a0 = 0.f, a1 = 0.f, a2 = 0.f, a3 = 0.f, a4 = 0.f, a5 = 0.f;
  for (int cb = beg; cb < end; cb += 256) {
    int mc = end - cb; if (mc > 256) mc = 256;
    if (tid < mc) s_e[tid] = ee[cb + tid];
    __syncthreads();
    for (int e = 0; e < mc; ++e) {
      uint2 r = s_e[e];
      float w = __uint_as_float(r.y);
      u32x3 v = *(const u32x3*)(base + (r.x + myoff));
      a0 += w * bflo(v.x); a1 += w * bfhi(v.x);
      a2 += w * bflo(v.y); a3 += w * bfhi(v.y);
      a4 += w * bflo(v.z); a5 += w * bfhi(v.z);
    }
    __syncthreads();
  }
  const int e0 = tid * 6;
  float r0 = sigm(a0 + s_b[e0 & 127]);
  float r1 = sigm(a1 + s_b[(e0 + 1) & 127]);
  float r2 = sigm(a2 + s_b[(e0 + 2) & 127]);
  float r3 = sigm(a3 + s_b[(e0 + 3) & 127]);
  float r4 = sigm(a4 + s_b[(e0 + 4) & 127]);
  float r5 = sigm(a5 + s_b[(e0 + 5) & 127]);
  u32x3 o;
  o.x = ((u32)f2bf(r1) << 16) | (u32)f2bf(r0);
  o.y = ((u32)f2bf(r3) << 16) | (u32)f2bf(r2);
  o.z = ((u32)f2bf(r5) << 16) | (u32)f2bf(r4);
  *(u32x3*)((char*)g + ((size_t)j * NTB + myoff)) = o;
}

// ---------------- output projection: out = h1 @ ow + ob ----------------
__global__ void k_out(const u16* __restrict__ h, const float* __restrict__ ow,
                      const float* __restrict__ ob, float* __restrict__ out, int M) {
  __shared__ float lw[HDIM * OUTD];
  __shared__ float lb[OUTD];
  int tid = threadIdx.x;  // 256
  for (int i = tid; i < HDIM * OUTD; i += 256) lw[i] = ow[i];
  if (tid < OUTD) lb[tid] = ob[tid];
  __syncthreads();
  int j = tid & 63;
  int nl = tid >> 6;
  int n = blockIdx.x * 4 + nl;
  if (n >= M) return;
  const u16* hr = h + (size_t)n * HDIM;
  float s = lb[j];
#pragma unroll 4
  for (int k = 0; k < HDIM; ++k) s += __uint_as_float(((u32)hr[k]) << 16) * lw[k * OUTD + j];
  out[(size_t)n * OUTD + j] = s;
}

// ---------------- host ----------------
extern "C" void kernel_launch(void* const* d_in, const int* in_sizes, int n_in,
                              void* d_out, int out_size, void* d_ws, size_t ws_size,
                              hipStream_t stream) {
  const float* x  = (const float*)d_in[0];
  const float* ea = (const float*)d_in[1];
  const int*   ei = (const int*)d_in[2];
  const float* gw[2] = { (const float*)d_in[3],  (const float*)d_in[13] };
  const float* gb[2] = { (const float*)d_in[4],  (const float*)d_in[14] };
  const float* wg[2][4] = {
    { (const float*)d_in[5],  (const float*)d_in[7],  (const float*)d_in[9],  (const float*)d_in[11] },
    { (const float*)d_in[15], (const float*)d_in[17], (const float*)d_in[19], (const float*)d_in[21] } };
  const float* bg[2][4] = {
    { (const float*)d_in[6],  (const float*)d_in[8],  (const float*)d_in[10], (const float*)d_in[12] },
    { (const float*)d_in[16], (const float*)d_in[18], (const float*)d_in[20], (const float*)d_in[22] } };
  const float* ow = (const float*)d_in[23];
  const float* ob = (const float*)d_in[24];
  float* out = (float*)d_out;

  const int N = in_sizes[0] / (HDIM * TSTEPS);
  const int E = in_sizes[2] / 2;
  const int nh = N * HDIM;
  const int tnh = TSTEPS * nh;

  // ---- arena (~206 MB, heavy aliasing; known-good budget is ~252 MB) ----
  size_t off = 0;
  auto alloc = [&](size_t bytes) -> void* {
    void* p = (char*)d_ws + off;
    off += (bytes + 255) & ~(size_t)255;
    return p;
  };
  u16* xb     = (u16*)alloc((size_t)tnh * 2);   // time-major x; later hosts XW1 (node-major) then H1 ping-pong
  u16* g_nm   = (u16*)alloc((size_t)tnh * 2);   // node-major g (layer0 then layer1)
  u16* h0_all = (u16*)alloc((size_t)(TSTEPS + 1) * nh * 2); // hosts XW0 before chain-0; then h0 slots
  float* cst  = (float*)alloc((size_t)nh * 4);  // single c-state, re-zeroed between chains
  uint2* ee   = (uint2*)alloc((size_t)(E + N) * 8);
  float* dis  = (float*)alloc((size_t)N * 4);
  int* cnt    = (int*)alloc((size_t)N * 4);
  int* cursor = (int*)alloc((size_t)N * 4);
  int* rp     = (int*)alloc((size_t)(N + 1) * 4);
  u16* gwT[2] = { (u16*)alloc(HDIM * HDIM * 2), (u16*)alloc(HDIM * HDIM * 2) };
  u16* w4T[2] = { (u16*)alloc(512 * 384 * 2),   (u16*)alloc(512 * 384 * 2) };
  float* b4[2] = { (float*)alloc(512 * 4), (float*)alloc(512 * 4) };
  alloc(131072);  // slack so benign OOB tile reads at the arena tail stay mapped

  u16* XW0 = h0_all;            // alias: node-major gcn0 output, dead before chain-0
  u16* XW1 = xb;                // alias: node-major gcn1 output, written after chain-0
  u16* H1[2] = { xb, xb + (size_t)nh };  // alias: h1 ping-pong, written after aggB1

  // ---- setup ----
  k_init<<<(N + 255) / 256, 256, 0, stream>>>(cnt, cursor, N);
  k_xpose<<<(nh + 255) / 256, 256, 0, stream>>>(x, xb, N);
  k_cnt<<<(E + 255) / 256, 256, 0, stream>>>(ei, cnt, E);
  k_scan<<<1, 1024, 0, stream>>>(cnt, rp, N);
  k_scatter<<<(E + 255) / 256, 256, 0, stream>>>(ei, ea, rp, cursor, ee, E);
  k_degcsr<<<N, 64, 0, stream>>>(rp, ee, dis, N);
  k_enrm<<<N, 64, 0, stream>>>(rp, dis, ee, N);
  for (int l = 0; l < 2; ++l) {
    k_wt<<<(HDIM * HDIM + 255) / 256, 256, 0, stream>>>(gw[l], gwT[l], HDIM, HDIM, HDIM);
    k_wt4<<<(512 * 384 + 255) / 256, 256, 0, stream>>>(wg[l][0], wg[l][1], wg[l][2], wg[l][3], w4T[l]);
    k_bias4<<<2, 256, 0, stream>>>(bg[l][0], bg[l][1], bg[l][2], bg[l][3], b4[l]);
  }

  const int nb = (N + 127) / 128;

  // ---- phase 0 (batched, layer 0) ----
  k_gcnlin<<<dim3(nb, TSTEPS), 256, 0, stream>>>(xb, gwT[0], XW0, N, nh);
  k_aggB<<<N, 256, 0, stream>>>(XW0, rp, ee, gb[0], g_nm, N);
  k_zero<<<(nh / 2 + 255) / 256, 256, 0, stream>>>((u32*)h0_all, nh / 2);  // h0_{-1} = 0 (slot 0)
  k_zero<<<(nh + 255) / 256, 256, 0, stream>>>((u32*)cst, nh);             // c0 = 0

  // ---- h0 chain (serial, K=384: [x_t | g0_t | h0_{t-1}]) ----
  for (int t = 0; t < TSTEPS; ++t)
    k_gate3<<<dim3(nb, 4), 256, 0, stream>>>(
        xb + (size_t)t * nh, HDIM,
        g_nm + (size_t)t * HDIM, NTMAJ,
        h0_all + (size_t)t * nh, HDIM,
        w4T[0], b4[0], cst, h0_all + (size_t)(t + 1) * nh, N);

  // ---- phase 1 (batched, layer 1) ----
  k_gcnlin<<<dim3(nb, TSTEPS), 256, 0, stream>>>(h0_all + nh, gwT[1], XW1, N, nh);
  k_aggB<<<N, 256, 0, stream>>>(XW1, rp, ee, gb[1], g_nm, N);
  k_zero<<<(nh / 2 + 255) / 256, 256, 0, stream>>>((u32*)H1[1], nh / 2);   // h1_{-1} = 0
  k_zero<<<(nh + 255) / 256, 256, 0, stream>>>((u32*)cst, nh);             // c1 = 0

  // ---- h1 chain (serial, K=384: [h0_t | g1_t | h1_{t-1}]) ----
  for (int t = 0; t < TSTEPS; ++t)
    k_gate3<<<dim3(nb, 4), 256, 0, stream>>>(
        h0_all + (size_t)(t + 1) * nh, HDIM,
        g_nm + (size_t)t * HDIM, NTMAJ,
        H1[(t + 1) & 1], HDIM,
        w4T[1], b4[1], cst, H1[t & 1], N);

  k_out<<<(N + 3) / 4, 256, 0, stream>>>(H1[1], ow, ob, out, N);
}

// Round 8
// 1469.492 us; speedup vs baseline: 1.0921x; 1.0921x over previous
//
#include <hip/hip_runtime.h>
#include <hip/hip_bf16.h>

typedef unsigned short u16;
typedef unsigned int   u32;
typedef __attribute__((ext_vector_type(8))) short bf16x8;
typedef __attribute__((ext_vector_type(4))) float f32x4;

#define HDIM 128
#define TSTEPS 12
#define OUTD 64
#define CH_T 3               /* timesteps per chunk */

#define AS1 __attribute__((address_space(1)))
#define AS3 __attribute__((address_space(3)))

__device__ __forceinline__ void glds16(const void* g, void* l) {
  __builtin_amdgcn_global_load_lds((const AS1 u32*)g, (AS3 u32*)l, 16, 0, 0);
}

__device__ __forceinline__ float bflo(u32 u) { return __uint_as_float(u << 16); }
__device__ __forceinline__ float bfhi(u32 u) { return __uint_as_float(u & 0xffff0000u); }
__device__ __forceinline__ u16 f2bf(float x) {
  union { float f; u32 u; } v; v.f = x;
  return (u16)((v.u + 0x7fffu + ((v.u >> 16) & 1u)) >> 16);
}
__device__ __forceinline__ float sigm(float x) { return 1.0f / (1.0f + __expf(-x)); }
__device__ __forceinline__ float tanh_f(float x) { return 1.0f - 2.0f / (__expf(2.0f * x) + 1.0f); }

// ---------------- setup kernels ----------------

__global__ void k_init(int* cnt, int* cursor, int N) {
  int i = blockIdx.x * 256 + threadIdx.x;
  if (i < N) { cnt[i] = 1; cursor[i] = 0; }   // cnt=1 reserves the self-loop slot
}

// x (N,128,12) f32 -> xb (12,N,128) bf16 (time-major)
__global__ void k_xpose(const float* __restrict__ x, u16* __restrict__ xb, int N) {
  int i = blockIdx.x * 256 + threadIdx.x;  // (n,f)
  if (i >= N * HDIM) return;
  const float* src = x + (size_t)i * 12;
  float4 a = *(const float4*)src;
  float4 b = *(const float4*)(src + 4);
  float4 c = *(const float4*)(src + 8);
  float v[12] = { a.x,a.y,a.z,a.w,b.x,b.y,b.z,b.w,c.x,c.y,c.z,c.w };
#pragma unroll
  for (int t = 0; t < 12; ++t) xb[(size_t)t * N * HDIM + i] = f2bf(v[t]);
}

__global__ void k_cnt(const int* __restrict__ ei, int* cnt, int E) {
  int e = blockIdx.x * 256 + threadIdx.x;
  if (e >= E) return;
  atomicAdd(&cnt[ei[E + e]], 1);
}

__global__ void k_scan(const int* __restrict__ cnt, int* __restrict__ rp, int n) {
  __shared__ int sums[1024];
  int tid = threadIdx.x;
  int chunk = (n + 1023) / 1024;
  int start = tid * chunk;
  int end = start + chunk; if (end > n) end = n;
  int s = 0;
  for (int i = start; i < end; ++i) s += cnt[i];
  sums[tid] = s;
  __syncthreads();
  for (int off = 1; off < 1024; off <<= 1) {
    int v = (tid >= off) ? sums[tid - off] : 0;
    __syncthreads();
    sums[tid] += v;
    __syncthreads();
  }
  int run = (tid == 0) ? 0 : sums[tid - 1];
  for (int i = start; i < end; ++i) { rp[i] = run; run += cnt[i]; }
  if (tid == 1023) rp[n] = sums[1023];
}

// edges -> interleaved {src_row_byteoff (256B slab rows), raw_w}; slot rp[col]+0 = self
__global__ void k_scatter(const int* __restrict__ ei, const float* __restrict__ ea,
                          const int* __restrict__ rp, int* cursor, uint2* ee, int E) {
  int e = blockIdx.x * 256 + threadIdx.x;
  if (e >= E) return;
  int row = ei[e], col = ei[E + e];
  int pos = atomicAdd(&cursor[col], 1);
  int idx = rp[col] + 1 + pos;
  ee[idx] = make_uint2((u32)row << 8, __float_as_uint(ea[e * 4 + 3]));
}

__global__ void k_degcsr(const int* __restrict__ rp, uint2* ee, float* dis, int N) {
  int j = blockIdx.x;
  int lane = threadIdx.x;  // 64
  int beg = rp[j], end = rp[j + 1];
  float s = 0.f;
  for (int i = beg + 1 + lane; i < end; i += 64) s += __uint_as_float(ee[i].y);
#pragma unroll
  for (int o = 32; o; o >>= 1) s += __shfl_down(s, o);
  if (lane == 0) {
    dis[j] = rsqrtf(1.0f + s);
    ee[beg] = make_uint2((u32)j << 8, __float_as_uint(1.0f));  // self-loop raw w = 1
  }
}

__global__ void k_enrm(const int* __restrict__ rp, const float* __restrict__ dis,
                       uint2* ee, int N) {
  int j = blockIdx.x;
  int lane = threadIdx.x;  // 64
  int beg = rp[j], end = rp[j + 1];
  float dj = dis[j];
  for (int i = beg + lane; i < end; i += 64) {
    uint2 q = ee[i];
    ee[i].y = __float_as_uint(dis[q.x >> 8] * __uint_as_float(q.y) * dj);
  }
}

// src (K,J) f32 row-major -> dst[j*ldK + k] bf16 (transposed)
__global__ void k_wt(const float* __restrict__ src, u16* __restrict__ dst, int K, int J, int ldK) {
  int idx = blockIdx.x * 256 + threadIdx.x;
  if (idx >= K * J) return;
  int k = idx / J, j = idx % J;
  dst[j * ldK + k] = f2bf(src[idx]);
}

// recurrent part of gate weights (zu rows 256..383), col-permuted p
__global__ void k_wt4r(const float* wf, const float* wi, const float* wo, const float* wc,
                       u16* __restrict__ dst) {
  int idx = blockIdx.x * 256 + threadIdx.x;  // 512*128
  if (idx >= 512 * 128) return;
  int p = idx / 128, k = idx % 128;
  int g = (p >> 4) & 3;
  int hc = (p & 15) | ((p >> 6) << 4);
  const float* w[4] = { wf, wi, wo, wc };
  dst[p * 128 + k] = f2bf(w[g][(256 + k) * HDIM + hc]);
}

// x+g part of gate weights (zu rows 0..255), col-permuted p
__global__ void k_wt4xg(const float* wf, const float* wi, const float* wo, const float* wc,
                        u16* __restrict__ dst) {
  int idx = blockIdx.x * 256 + threadIdx.x;  // 512*256
  if (idx >= 512 * 256) return;
  int p = idx / 256, k = idx % 256;
  int g = (p >> 4) & 3;
  int hc = (p & 15) | ((p >> 6) << 4);
  const float* w[4] = { wf, wi, wo, wc };
  dst[p * 256 + k] = f2bf(w[g][k * HDIM + hc]);
}

__global__ void k_bias4(const float* bf, const float* bi, const float* bo, const float* bc,
                        float* dst) {
  int p = blockIdx.x * 256 + threadIdx.x;
  if (p >= 512) return;
  int g = (p >> 4) & 3;
  int hc = (p & 15) | ((p >> 6) << 4);
  const float* b[4] = { bf, bi, bo, bc };
  dst[p] = b[g][hc];
}

// ---- chunked GCN linear: out slab tt (time-major) = A slab tt @ gwT^T, grid (nb, CH_T) ----
__global__ __launch_bounds__(256)
void k_gcnlin(const u16* __restrict__ A, const u16* __restrict__ wt,
              u16* __restrict__ out, int N, int nh) {
  __shared__ u16 lA[128 * 32];
  __shared__ u16 lB[128 * 32];
  const int t = blockIdx.y;
  const int tid = threadIdx.x;
  const int row0 = blockIdx.x * 128;
  const int wave = tid >> 6, lane = tid & 63;
  const int wm = (wave >> 1) * 64, wn = (wave & 1) * 64;
  const int fr = lane & 15, fk = (lane >> 4) * 8;
  const int lr = tid >> 2, lc = (tid & 3) * 8;
  u16* ldA = lA + wave * 512;
  u16* ldB = lB + wave * 512;
  const u16* ga1 = A + (size_t)t * nh + (size_t)(row0 + lr) * HDIM + lc;
  const u16* ga2 = ga1 + (size_t)64 * HDIM;
  const u16* gb1 = wt + (size_t)lr * HDIM + lc;
  const u16* gb2 = gb1 + (size_t)64 * HDIM;

  f32x4 acc[4][4] = {};
  for (int k0 = 0; k0 < 128; k0 += 32) {
    glds16(ga1 + k0, ldA);
    glds16(ga2 + k0, ldA + 2048);
    glds16(gb1 + k0, ldB);
    glds16(gb2 + k0, ldB + 2048);
    __syncthreads();
    bf16x8 af[4], bfx[4];
#pragma unroll
    for (int m = 0; m < 4; ++m) af[m]  = *(const bf16x8*)&lA[(wm + m * 16 + fr) * 32 + fk];
#pragma unroll
    for (int n = 0; n < 4; ++n) bfx[n] = *(const bf16x8*)&lB[(wn + n * 16 + fr) * 32 + fk];
#pragma unroll
    for (int m = 0; m < 4; ++m)
#pragma unroll
      for (int n = 0; n < 4; ++n)
        acc[m][n] = __builtin_amdgcn_mfma_f32_16x16x32_bf16(af[m], bfx[n], acc[m][n], 0, 0, 0);
    __syncthreads();
  }
  const int fq4 = (lane >> 4) * 4;
#pragma unroll
  for (int m = 0; m < 4; ++m)
#pragma unroll
    for (int n = 0; n < 4; ++n) {
      const int colg = wn + n * 16 + fr;
#pragma unroll
      for (int i = 0; i < 4; ++i) {
        const int rowg = row0 + wm + m * 16 + fq4 + i;
        if (rowg < N) out[(size_t)t * nh + (size_t)rowg * HDIM + colg] = f2bf(acc[m][n][i]);
      }
    }
}

// ---- chunked partial GEMM: P[tt][node][512] = [segX_tt | segG_tt] @ wxg^T, grid (nb,4,CH_T) ----
__global__ __launch_bounds__(256)
void k_partial(const u16* __restrict__ segX, const u16* __restrict__ segG,
               const u16* __restrict__ wxg, u16* __restrict__ outP, int N, int nh) {
  __shared__ u16 lA[128 * 32];
  __shared__ u16 lB[128 * 32];
  const int tt = blockIdx.z;
  const int col0 = blockIdx.y * 128;
  const int tid = threadIdx.x;
  const int row0 = blockIdx.x * 128;
  const int wave = tid >> 6, lane = tid & 63;
  const int wm = (wave >> 1) * 64, wn = (wave & 1) * 64;
  const int fr = lane & 15, fk = (lane >> 4) * 8;
  const int lr = tid >> 2, lc = (tid & 3) * 8;
  u16* ldA = lA + wave * 512;
  u16* ldB = lB + wave * 512;
  const u16* aX1 = segX + (size_t)tt * nh + (size_t)(row0 + lr) * HDIM + lc;
  const u16* aX2 = aX1 + (size_t)64 * HDIM;
  const u16* aG1 = segG + (size_t)tt * nh + (size_t)(row0 + lr) * HDIM + lc;
  const u16* aG2 = aG1 + (size_t)64 * HDIM;
  const u16* b1 = wxg + (size_t)(col0 + lr) * 256 + lc;
  const u16* b2 = b1 + (size_t)64 * 256;

  f32x4 acc[4][4] = {};
#pragma unroll
  for (int ks = 0; ks < 8; ++ks) {
    const u16* s1 = (ks < 4) ? (aX1 + ks * 32) : (aG1 + (ks - 4) * 32);
    const u16* s2 = (ks < 4) ? (aX2 + ks * 32) : (aG2 + (ks - 4) * 32);
    glds16(s1, ldA);
    glds16(s2, ldA + 2048);
    glds16(b1 + ks * 32, ldB);
    glds16(b2 + ks * 32, ldB + 2048);
    __syncthreads();
    bf16x8 af[4], bfx[4];
#pragma unroll
    for (int m = 0; m < 4; ++m) af[m]  = *(const bf16x8*)&lA[(wm + m * 16 + fr) * 32 + fk];
#pragma unroll
    for (int n = 0; n < 4; ++n) bfx[n] = *(const bf16x8*)&lB[(wn + n * 16 + fr) * 32 + fk];
#pragma unroll
    for (int m = 0; m < 4; ++m)
#pragma unroll
      for (int n = 0; n < 4; ++n)
        acc[m][n] = __builtin_amdgcn_mfma_f32_16x16x32_bf16(af[m], bfx[n], acc[m][n], 0, 0, 0);
    __syncthreads();
  }
  const int fq4 = (lane >> 4) * 4;
  u16* outT = outP + (size_t)tt * N * 512;
#pragma unroll
  for (int m = 0; m < 4; ++m)
#pragma unroll
    for (int n = 0; n < 4; ++n) {
      const int colg = col0 + wn + n * 16 + fr;
#pragma unroll
      for (int i = 0; i < 4; ++i) {
        const int rowg = row0 + wm + m * 16 + fq4 + i;
        if (rowg < N) outT[(size_t)rowg * 512 + colg] = f2bf(acc[m][n][i]);
      }
    }
}

// ---- recurrent gate GEMM (K=128, 64-row tiles) + partial + LSTM epilogue, grid (ceil(M/64),4) ----
__global__ __launch_bounds__(256)
void k_gate64(const u16* __restrict__ hprev, const u16* __restrict__ wr,
              const float* __restrict__ b4p, const u16* __restrict__ pp,
              float* __restrict__ cst, u16* __restrict__ hout, int M) {
  __shared__ u16 lA[64 * 32];
  __shared__ u16 lB[128 * 32];
  const int col0 = blockIdx.y * 128;
  const int row0 = blockIdx.x * 64;
  const int tid = threadIdx.x;
  const int wave = tid >> 6, lane = tid & 63;
  const int wm = (wave >> 1) * 32, wn = (wave & 1) * 64;
  const int fr = lane & 15, fk = (lane >> 4) * 8;
  const int lr = tid >> 2, lc = (tid & 3) * 8;
  u16* ldA = lA + wave * 512;
  u16* ldB = lB + wave * 512;
  const u16* ga  = hprev + (size_t)(row0 + lr) * HDIM + lc;
  const u16* gb1 = wr + (size_t)(col0 + lr) * HDIM + lc;
  const u16* gb2 = gb1 + (size_t)64 * HDIM;

  f32x4 acc[2][4] = {};
#pragma unroll
  for (int k0 = 0; k0 < 128; k0 += 32) {
    glds16(ga + k0, ldA);
    glds16(gb1 + k0, ldB);
    glds16(gb2 + k0, ldB + 2048);
    __syncthreads();
    bf16x8 af[2], bfx[4];
#pragma unroll
    for (int m = 0; m < 2; ++m) af[m]  = *(const bf16x8*)&lA[(wm + m * 16 + fr) * 32 + fk];
#pragma unroll
    for (int n = 0; n < 4; ++n) bfx[n] = *(const bf16x8*)&lB[(wn + n * 16 + fr) * 32 + fk];
#pragma unroll
    for (int m = 0; m < 2; ++m)
#pragma unroll
      for (int n = 0; n < 4; ++n)
        acc[m][n] = __builtin_amdgcn_mfma_f32_16x16x32_bf16(af[m], bfx[n], acc[m][n], 0, 0, 0);
    __syncthreads();
  }

  const int fq4 = (lane >> 4) * 4;
  const int hc = fr | ((blockIdx.y * 2 + (wave & 1)) << 4);
  const int colbase = col0 + wn + fr;
  const float bb0 = b4p[colbase];
  const float bb1 = b4p[colbase + 16];
  const float bb2 = b4p[colbase + 32];
  const float bb3 = b4p[colbase + 48];
#pragma unroll
  for (int m = 0; m < 2; ++m)
#pragma unroll
    for (int i = 0; i < 4; ++i) {
      const int rowg = row0 + wm + m * 16 + fq4 + i;
      if (rowg < M) {
        const u16* pr = pp + (size_t)rowg * 512 + colbase;
        float f_ = sigm(acc[m][0][i] + bb0 + bflo(pr[0]));
        float i_ = sigm(acc[m][1][i] + bb1 + bflo(pr[16]));
        float o_ = sigm(acc[m][2][i] + bb2 + bflo(pr[32]));
        float cd = tanh_f(acc[m][3][i] + bb3 + bflo(pr[48]));
        size_t idx = (size_t)rowg * HDIM + hc;
        float cn = f_ * cst[idx] + i_ * cd;
        cst[idx] = cn;
        hout[idx] = f2bf(o_ * tanh_f(cn));
      }
    }
}

// ---- t=0 cell: h_prev = 0, c_prev = 0 -> pure elementwise from partial; also inits cst ----
__global__ void k_cell0(const u16* __restrict__ pp, const float* __restrict__ b4p,
                        float* __restrict__ cst, u16* __restrict__ hout, int total) {
  int i = blockIdx.x * 256 + threadIdx.x;
  if (i >= total) return;
  int node = i >> 7, hc = i & 127;
  int p0 = (hc & 15) | ((hc >> 4) << 6);
  const u16* pr = pp + (size_t)node * 512 + p0;
  float i_ = sigm(bflo(pr[16]) + b4p[p0 + 16]);
  float o_ = sigm(bflo(pr[32]) + b4p[p0 + 32]);
  float cd = tanh_f(bflo(pr[48]) + b4p[p0 + 48]);
  float cn = i_ * cd;                 // f*c_prev = 0
  cst[i] = cn;
  hout[i] = f2bf(o_ * tanh_f(cn));
}

// ---- time-major batched aggregation + sigmoid (round-4 proven), grid (CH_T*N, 64) ----
__global__ void k_agg(const u16* __restrict__ xw, const int* __restrict__ rp,
                      const uint2* __restrict__ ee, const float* __restrict__ gb,
                      u16* __restrict__ g, int N) {
  __shared__ uint2 s_e[64];
  const char* xwb = (const char*)xw;
  int bid = blockIdx.x;
  int j = bid % N;
  u32 tbase = (u32)(bid - j) << 8;   // byte offset of this t-slab
  int lane = threadIdx.x;            // 64
  int beg = rp[j], end = rp[j + 1];
  const int sl = lane & 31, half = lane >> 5;
  const u32 slB = (u32)sl * 8;
  float a0 = 0.f, a1 = 0.f, a2 = 0.f, a3 = 0.f;
  for (int cb = beg; cb < end; cb += 64) {
    int mc = end - cb; if (mc > 64) mc = 64;
    uint2 q;
    if (lane < mc) { q = ee[cb + lane]; q.x += tbase; }
    else { q.x = tbase; q.y = 0u; }   // pad: valid addr, zero weight
    s_e[lane] = q;
    __syncthreads();
    int np = (mc + 1) >> 1;
    for (int p = 0; p < np; ++p) {
      uint2 r = s_e[p * 2 + half];
      float w = __uint_as_float(r.y);
      uint2 v = *(const uint2*)(xwb + (r.x + slB));
      a0 += w * bflo(v.x);
      a1 += w * bfhi(v.x);
      a2 += w * bflo(v.y);
      a3 += w * bfhi(v.y);
    }
    __syncthreads();
  }
  a0 += __shfl_xor(a0, 32);
  a1 += __shfl_xor(a1, 32);
  a2 += __shfl_xor(a2, 32);
  a3 += __shfl_xor(a3, 32);
  if (half == 0) {
    float4 bv = *(const float4*)(gb + sl * 4);
    a0 = sigm(a0 + bv.x); a1 = sigm(a1 + bv.y);
    a2 = sigm(a2 + bv.z); a3 = sigm(a3 + bv.w);
    uint2 o;
    o.x = ((u32)f2bf(a1) << 16) | (u32)f2bf(a0);
    o.y = ((u32)f2bf(a3) << 16) | (u32)f2bf(a2);
    *(uint2*)((char*)g + (((size_t)bid) << 8) + slB) = o;
  }
}

// ---------------- output projection: out = h1 @ ow + ob ----------------
__global__ void k_out(const u16* __restrict__ h, const float* __restrict__ ow,
                      const float* __restrict__ ob, float* __restrict__ out, int M) {
  __shared__ float lw[HDIM * OUTD];
  __shared__ float lb[OUTD];
  int tid = threadIdx.x;  // 256
  for (int i = tid; i < HDIM * OUTD; i += 256) lw[i] = ow[i];
  if (tid < OUTD) lb[tid] = ob[tid];
  __syncthreads();
  int j = tid & 63;
  int nl = tid >> 6;
  int n = blockIdx.x * 4 + nl;
  if (n >= M) return;
  const u16* hr = h + (size_t)n * HDIM;
  float s = lb[j];
#pragma unroll 4
  for (int k = 0; k < HDIM; ++k) s += __uint_as_float(((u32)hr[k]) << 16) * lw[k * OUTD + j];
  out[(size_t)n * OUTD + j] = s;
}

// ---------------- host ----------------
extern "C" void kernel_launch(void* const* d_in, const int* in_sizes, int n_in,
                              void* d_out, int out_size, void* d_ws, size_t ws_size,
                              hipStream_t stream) {
  const float* x  = (const float*)d_in[0];
  const float* ea = (const float*)d_in[1];
  const int*   ei = (const int*)d_in[2];
  const float* gw[2] = { (const float*)d_in[3],  (const float*)d_in[13] };
  const float* gb[2] = { (const float*)d_in[4],  (const float*)d_in[14] };
  const float* wg[2][4] = {
    { (const float*)d_in[5],  (const float*)d_in[7],  (const float*)d_in[9],  (const float*)d_in[11] },
    { (const float*)d_in[15], (const float*)d_in[17], (const float*)d_in[19], (const float*)d_in[21] } };
  const float* bg[2][4] = {
    { (const float*)d_in[6],  (const float*)d_in[8],  (const float*)d_in[10], (const float*)d_in[12] },
    { (const float*)d_in[16], (const float*)d_in[18], (const float*)d_in[20], (const float*)d_in[22] } };
  const float* ow = (const float*)d_in[23];
  const float* ob = (const float*)d_in[24];
  float* out = (float*)d_out;

  const int N = in_sizes[0] / (HDIM * TSTEPS);
  const int E = in_sizes[2] / 2;
  const int nh = N * HDIM;
  const int tnh = TSTEPS * nh;

  // ---- arena (~232 MB; known-good budget ~247 MB) ----
  size_t off = 0;
  auto alloc = [&](size_t bytes) -> void* {
    void* p = (char*)d_ws + off;
    off += (bytes + 255) & ~(size_t)255;
    return p;
  };
  u16* xb     = (u16*)alloc((size_t)tnh * 2);            // time-major x; hosts H1 ping-pong in layer 1
  u16* h0_all = (u16*)alloc((size_t)TSTEPS * nh * 2);    // h0_t, t=0..11
  u16* XWc    = (u16*)alloc((size_t)CH_T * nh * 2);      // chunk gcn-linear out (time-major slabs)
  u16* gc     = (u16*)alloc((size_t)CH_T * nh * 2);      // chunk g (time-major slabs)
  u16* Pc     = (u16*)alloc((size_t)CH_T * N * 512 * 2); // chunk partial [tt][node][512]
  float* cst  = (float*)alloc((size_t)nh * 4);           // c-state (written by cell0 at each chain start)
  uint2* ee   = (uint2*)alloc((size_t)(E + N) * 8);
  float* dis  = (float*)alloc((size_t)N * 4);
  int* cnt    = (int*)alloc((size_t)N * 4);
  int* cursor = (int*)alloc((size_t)N * 4);
  int* rp     = (int*)alloc((size_t)(N + 1) * 4);
  u16* gwT[2]  = { (u16*)alloc(HDIM * HDIM * 2), (u16*)alloc(HDIM * HDIM * 2) };
  u16* w4r[2]  = { (u16*)alloc(512 * 128 * 2), (u16*)alloc(512 * 128 * 2) };
  u16* w4xg[2] = { (u16*)alloc(512 * 256 * 2), (u16*)alloc(512 * 256 * 2) };
  float* b4[2] = { (float*)alloc(512 * 4), (float*)alloc(512 * 4) };
  alloc(131072);  // slack so benign OOB tile reads at the arena tail stay mapped

  u16* H1[2] = { xb, xb + (size_t)nh };  // alias: xb dead after layer-0's last partial

  // ---- setup ----
  k_init<<<(N + 255) / 256, 256, 0, stream>>>(cnt, cursor, N);
  k_xpose<<<(nh + 255) / 256, 256, 0, stream>>>(x, xb, N);
  k_cnt<<<(E + 255) / 256, 256, 0, stream>>>(ei, cnt, E);
  k_scan<<<1, 1024, 0, stream>>>(cnt, rp, N);
  k_scatter<<<(E + 255) / 256, 256, 0, stream>>>(ei, ea, rp, cursor, ee, E);
  k_degcsr<<<N, 64, 0, stream>>>(rp, ee, dis, N);
  k_enrm<<<N, 64, 0, stream>>>(rp, dis, ee, N);
  for (int l = 0; l < 2; ++l) {
    k_wt<<<(HDIM * HDIM + 255) / 256, 256, 0, stream>>>(gw[l], gwT[l], HDIM, HDIM, HDIM);
    k_wt4r<<<(512 * 128 + 255) / 256, 256, 0, stream>>>(wg[l][0], wg[l][1], wg[l][2], wg[l][3], w4r[l]);
    k_wt4xg<<<(512 * 256 + 255) / 256, 256, 0, stream>>>(wg[l][0], wg[l][1], wg[l][2], wg[l][3], w4xg[l]);
    k_bias4<<<2, 256, 0, stream>>>(bg[l][0], bg[l][1], bg[l][2], bg[l][3], b4[l]);
  }

  const int nb = (N + 127) / 128;
  const int nb64 = (N + 63) / 64;
  const int NCH = TSTEPS / CH_T;

  for (int l = 0; l < 2; ++l) {
    const u16* src = (l == 0) ? xb : h0_all;
    for (int c = 0; c < NCH; ++c) {
      const u16* srcC = src + (size_t)c * CH_T * nh;
      k_gcnlin<<<dim3(nb, CH_T), 256, 0, stream>>>(srcC, gwT[l], XWc, N, nh);
      k_agg<<<CH_T * N, 64, 0, stream>>>(XWc, rp, ee, gb[l], gc, N);
      k_partial<<<dim3(nb, 4, CH_T), 256, 0, stream>>>(srcC, gc, w4xg[l], Pc, N, nh);
      for (int tt = 0; tt < CH_T; ++tt) {
        const int t = c * CH_T + tt;
        u16* hdst = (l == 0) ? (h0_all + (size_t)t * nh) : H1[t & 1];
        const u16* Pt = Pc + (size_t)tt * N * 512;
        if (t == 0) {
          k_cell0<<<(nh + 255) / 256, 256, 0, stream>>>(Pt, b4[l], cst, hdst, nh);
        } else {
          const u16* hsrc = (l == 0) ? (h0_all + (size_t)(t - 1) * nh) : H1[(t - 1) & 1];
          k_gate64<<<dim3(nb64, 4), 256, 0, stream>>>(hsrc, w4r[l], b4[l], Pt, cst, hdst, N);
        }
      }
    }
  }
  k_out<<<(N + 3) / 4, 256, 0, stream>>>(H1[1], ow, ob, out, N);
}